// Round 6
// baseline (129.542 us; speedup 1.0000x reference)
//
#include <hip/hip_runtime.h>

#define NS 1024      // N samples
#define MM 64        // M patches
#define CC 4         // C compartments
#define NSTEPS 100
#define CLIPMAX 1e10f

// Broadcast lane k's value to all lanes via v_readlane (VALU, no LDS pipe).
__device__ __forceinline__ float rdlane(float v, int k) {
    return __uint_as_float(__builtin_amdgcn_readlane(__float_as_uint(v), k));
}

// 2 waves per sample (128 threads). Wave w owns j,k in [w*32, w*32+32):
//   Gcol[jj] = beta*Rt[n, lane, w*32+jj]/ntot    (phase A partial product)
//   Rrow[kk] = R[n, lane, w*32+kk]               (phase B partial matvec)
// Only duplicated work: phase C (~28 inst) + p/ninf combine (~6) -> per-sample
// issue ~1.2x the single-wave r3 version, but 2048 waves = 2/SIMD gives the
// latency hiding r2-r4 (1 wave/SIMD) structurally lacked. 2 barriers/step,
// each coupling only a wave PAIR (r5's 4-wave barriers convoyed).
__global__ __launch_bounds__(128, 2) void metapop_kernel(
    const float* __restrict__ R,     // (NS, MM, MM)
    const float* __restrict__ T,     // (NS, CC, CC)
    const float* __restrict__ rho0,  // (NS, MM, CC)
    const float* __restrict__ beta,  // (NS,)
    float* __restrict__ out)         // (NSTEPS, NS, MM, CC)
{
    const int n    = blockIdx.x;
    const int t    = threadIdx.x;
    const int lane = t & 63;
    const int w    = t >> 6;       // wave id 0..1
    const int base = w * 32;

    __shared__ float ppart[2][MM];   // phase A partial products
    __shared__ float sp[2][MM];      // phase B partial sums

    const float* Rn = R + (size_t)n * (MM * MM);

    // ---- Rrow: this wave's 32 columns of row `lane` (8x float4) ----
    float Rrow[32];
    {
        const float4* p4 = (const float4*)(Rn + lane * MM + base);
        #pragma unroll
        for (int q = 0; q < 8; ++q) {
            float4 v = p4[q];
            Rrow[4*q+0] = v.x; Rrow[4*q+1] = v.y;
            Rrow[4*q+2] = v.z; Rrow[4*q+3] = v.w;
        }
    }

    // ---- ntot: column sums, split over row halves ----
    {
        float s = 0.f;
        #pragma unroll
        for (int ii = 0; ii < 32; ++ii) s += Rn[(base + ii) * MM + lane];
        ppart[w][lane] = s;
    }
    __syncthreads();
    const float binv = beta[n] / (ppart[0][lane] + ppart[1][lane]);
    __syncthreads();   // ppart free for reuse

    // ---- Gcol: this wave's 32 j's of the transposed-gather matrix ----
    // Rt[n,i,j] = R[(i&15)*64+j, (n&15)*4+(i>>4), n>>4]
    float Gcol[32];
    {
        const int q     = n >> 4;
        const int a     = ((n & 15) << 2) + (lane >> 4);
        const int sbase = (lane & 15) << 6;
        #pragma unroll
        for (int jj = 0; jj < 32; ++jj) {
            int j = base + jj;
            float v = R[(size_t)(sbase + j) * (MM * MM) + a * MM + q];
            Gcol[jj] = v * rdlane(binv, j);
        }
    }

    // ---- pin state registers (r2 lesson: compiler sinks loads otherwise) ----
    #pragma unroll
    for (int k = 0; k < 32; ++k) asm volatile("" : "+v"(Rrow[k]));
    #pragma unroll
    for (int j = 0; j < 32; ++j) asm volatile("" : "+v"(Gcol[j]));

    // ---- T[n] (uniform -> scalar regs) and rho0 (duplicated in both waves) ----
    float tt[CC][CC];
    {
        const float* Tn = T + n * (CC * CC);
        #pragma unroll
        for (int k = 0; k < CC; ++k)
            #pragma unroll
            for (int l = 0; l < CC; ++l)
                tt[k][l] = Tn[k * CC + l];
    }
    float rh[CC];
    {
        float4 v = *(const float4*)(rho0 + (size_t)n * (MM * CC) + lane * CC);
        rh[0] = v.x; rh[1] = v.y; rh[2] = v.z; rh[3] = v.w;
    }

    // each wave stores half the trajectory rows -> balanced issue streams
    float* ob = out + (size_t)n * (MM * CC) + lane * CC;
    const size_t stride = (size_t)NS * MM * CC;
    const bool storer = (lane >> 5) == w;

    for (int step = 0; step < NSTEPS; ++step) {
        // trajectory records PRE-update state (coalesced float4, half per wave)
        if (storer)
            *(float4*)(ob + (size_t)step * stride) =
                make_float4(rh[0], rh[1], rh[2], rh[3]);

        // phase A partial (lane = i): prod over this wave's 32 j's, 2 chains
        const float r1 = rh[1];
        float pr0 = 1.f, pr1 = 1.f;
        #pragma unroll
        for (int jj = 0; jj < 16; ++jj) {
            pr0 *= 1.f - r1 * Gcol[jj];
            pr1 *= 1.f - r1 * Gcol[jj + 16];
        }
        const float pa = pr0 * pr1;
        ppart[w][lane] = pa;
        __syncthreads();   // barrier 1

        // full p at every lane of both waves (1 LDS read + 2 VALU)
        const float p = 1.f - pa * ppart[w ^ 1][lane];

        // phase B partial (lane = j): sum over this wave's 32 k's, 2 chains
        float s0 = 0.f, s1 = 0.f;
        #pragma unroll
        for (int kk = 0; kk < 16; ++kk) {
            s0 += Rrow[kk]      * rdlane(p, base + kk);
            s1 += Rrow[kk + 16] * rdlane(p, base + kk + 16);
        }
        const float sw = s0 + s1;
        sp[w][lane] = sw;
        __syncthreads();   // barrier 2

        const float ssum = sw + sp[w ^ 1][lane];
        const float sr   = (rh[0] + rh[1]) + (rh[2] + rh[3]);
        const float ninf = (1.f - sr) * ssum;

        // phase C (lane-local, duplicated in both waves -> rho stays in regs)
        float nr[CC];
        #pragma unroll
        for (int l = 0; l < CC; ++l) {
            float v = rh[0] * tt[0][l] + rh[1] * tt[1][l]
                    + rh[2] * tt[2][l] + rh[3] * tt[3][l];
            if (l == 0) v += ninf;
            nr[l] = fminf(fmaxf(v, 0.f), CLIPMAX);
        }
        #pragma unroll
        for (int l = 0; l < CC; ++l) rh[l] = nr[l];
    }
}

extern "C" void kernel_launch(void* const* d_in, const int* in_sizes, int n_in,
                              void* d_out, int out_size, void* d_ws, size_t ws_size,
                              hipStream_t stream) {
    const float* R    = (const float*)d_in[0];
    const float* T    = (const float*)d_in[1];
    const float* rho0 = (const float*)d_in[2];
    const float* beta = (const float*)d_in[3];
    float* out = (float*)d_out;
    hipLaunchKernelGGL(metapop_kernel, dim3(NS), dim3(128), 0, stream,
                       R, T, rho0, beta, out);
}

// Round 7
// 77.996 us; speedup vs baseline: 1.6609x; 1.6609x over previous
//
#include <hip/hip_runtime.h>

typedef __attribute__((ext_vector_type(2))) float f32x2;

#define NS 1024      // N samples
#define MM 64        // M patches
#define CC 4         // C compartments
#define NSTEPS 100
#define CLIPMAX 1e10f

// Broadcast lane k's value to all lanes via v_readlane.
__device__ __forceinline__ float rdlane(float v, int k) {
    return __uint_as_float(__builtin_amdgcn_readlane(__float_as_uint(v), k));
}
// Force a (wave-uniform) value into an SGPR.
__device__ __forceinline__ float sfirst(float v) {
    return __uint_as_float(__builtin_amdgcn_readfirstlane(__float_as_uint(v)));
}

// One wave per sample, barrier-free (r3 structure). Register residency fixed
// by an opaque-zero ADD (not asm ties): fz==0 lives in an SGPR the compiler
// can't see through, so Rrow/Gcol become computed values (load+add chains)
// that can't be remat-sunk into the time loop, and get plain VGPR homes
// (r3/r6's "+v" pins forced AGPR homes + accvgpr ping-pong, VGPR_Count 60-80).
// Phase A uses packed f32x2 math (v_pk_fma/v_pk_mul); T sits in SGPRs.
__global__ __launch_bounds__(64, 1) void metapop_kernel(
    const float* __restrict__ R,     // (NS, MM, MM)
    const float* __restrict__ T,     // (NS, CC, CC)
    const float* __restrict__ rho0,  // (NS, MM, CC)
    const float* __restrict__ beta,  // (NS,)
    float* __restrict__ out)         // (NSTEPS, NS, MM, CC)
{
    const int n    = blockIdx.x;
    const int lane = threadIdx.x;    // 0..63

    const float* Rn = R + (size_t)n * (MM * MM);

    // opaque zero in an SGPR
    float fz;
    asm volatile("s_mov_b32 %0, 0" : "=s"(fz));

    // ---- Rrow pairs: Rrow[k2] = (R[n,lane,2k2], R[n,lane,2k2+1]) ----
    f32x2 Rrow[32];
    {
        const float4* p4 = (const float4*)(Rn + lane * MM);
        #pragma unroll
        for (int q = 0; q < 16; ++q) {
            float4 v = p4[q];
            Rrow[2*q]   = (f32x2){v.x + fz, v.y + fz};
            Rrow[2*q+1] = (f32x2){v.z + fz, v.w + fz};
        }
    }

    // ---- ntot[lane] = sum_i R[n,i,lane] (coalesced per i; L1/L2-hot) ----
    float nt = 0.f;
    #pragma unroll
    for (int i = 0; i < MM; ++i) nt += Rn[i * MM + lane];
    const float binv = beta[n] / nt;   // lane j holds beta/ntot[j]

    // ---- Gcol pairs via the transpose bijection ----
    // Rt[n,i,j] = R[(i&15)*64+j, (n&15)*4+(i>>4), n>>4]
    f32x2 Gcol[32];
    {
        const int q     = n >> 4;
        const int a     = ((n & 15) << 2) + (lane >> 4);
        const int sbase = (lane & 15) << 6;
        #pragma unroll
        for (int j2 = 0; j2 < 32; ++j2) {
            const int j0 = 2 * j2, j1 = 2 * j2 + 1;
            float v0 = R[(size_t)(sbase + j0) * (MM * MM) + a * MM + q];
            float v1 = R[(size_t)(sbase + j1) * (MM * MM) + a * MM + q];
            Gcol[j2] = (f32x2){v0 * rdlane(binv, j0) + fz,
                               v1 * rdlane(binv, j1) + fz};
        }
    }

    // ---- T[n]: wave-uniform -> force into SGPRs ----
    float tt[CC][CC];
    {
        const float* Tn = T + n * (CC * CC);
        #pragma unroll
        for (int k = 0; k < CC; ++k)
            #pragma unroll
            for (int l = 0; l < CC; ++l)
                tt[k][l] = sfirst(Tn[k * CC + l]);
    }

    // ---- rho0 ----
    float rh[CC];
    {
        float4 v = *(const float4*)(rho0 + (size_t)n * (MM * CC) + lane * CC);
        rh[0] = v.x; rh[1] = v.y; rh[2] = v.z; rh[3] = v.w;
    }

    float* ob = out + (size_t)n * (MM * CC) + lane * CC;
    const size_t stride = (size_t)NS * MM * CC;

    for (int step = 0; step < NSTEPS; ++step) {
        // trajectory records PRE-update state; coalesced float4, fire-and-forget
        *(float4*)(ob + (size_t)step * stride) =
            make_float4(rh[0], rh[1], rh[2], rh[3]);

        // phase A (lane = i): p = 1 - prod_j (1 - rho1*Gcol[j]); packed, 4 chains
        const float r1  = rh[1];
        const f32x2 r1v = {r1, r1};
        const f32x2 one = {1.f, 1.f};
        f32x2 pa = one, pb = one, pc = one, pd = one;
        #pragma unroll
        for (int j2 = 0; j2 < 8; ++j2) {
            pa *= one - r1v * Gcol[j2];
            pb *= one - r1v * Gcol[j2 + 8];
            pc *= one - r1v * Gcol[j2 + 16];
            pd *= one - r1v * Gcol[j2 + 24];
        }
        const f32x2 pq = (pa * pb) * (pc * pd);
        const float p  = 1.f - pq.x * pq.y;

        // phase B (lane = j): s = sum_k Rrow[k]*p[k]; readlane broadcast, 4 chains
        float s0 = 0.f, s1 = 0.f, s2 = 0.f, s3 = 0.f;
        #pragma unroll
        for (int k2 = 0; k2 < 8; ++k2) {
            const f32x2 rA = Rrow[k2],      rB = Rrow[k2 + 8];
            const f32x2 rC = Rrow[k2 + 16], rD = Rrow[k2 + 24];
            s0 += rA.x * rdlane(p, 2*k2)      + rA.y * rdlane(p, 2*k2 + 1);
            s1 += rB.x * rdlane(p, 2*k2 + 16) + rB.y * rdlane(p, 2*k2 + 17);
            s2 += rC.x * rdlane(p, 2*k2 + 32) + rC.y * rdlane(p, 2*k2 + 33);
            s3 += rD.x * rdlane(p, 2*k2 + 48) + rD.y * rdlane(p, 2*k2 + 49);
        }
        const float ssum = (s0 + s1) + (s2 + s3);
        const float sr   = (rh[0] + rh[1]) + (rh[2] + rh[3]);
        const float ninf = (1.f - sr) * ssum;

        // phase C (lane-local): rho_new[l] = sum_k rho[k]*T[k,l] (+ninf at l=0)
        float nr[CC];
        #pragma unroll
        for (int l = 0; l < CC; ++l) {
            float v = rh[0] * tt[0][l] + rh[1] * tt[1][l]
                    + rh[2] * tt[2][l] + rh[3] * tt[3][l];
            if (l == 0) v += ninf;
            nr[l] = fminf(fmaxf(v, 0.f), CLIPMAX);
        }
        #pragma unroll
        for (int l = 0; l < CC; ++l) rh[l] = nr[l];
    }
}

extern "C" void kernel_launch(void* const* d_in, const int* in_sizes, int n_in,
                              void* d_out, int out_size, void* d_ws, size_t ws_size,
                              hipStream_t stream) {
    const float* R    = (const float*)d_in[0];
    const float* T    = (const float*)d_in[1];
    const float* rho0 = (const float*)d_in[2];
    const float* beta = (const float*)d_in[3];
    float* out = (float*)d_out;
    hipLaunchKernelGGL(metapop_kernel, dim3(NS), dim3(64), 0, stream,
                       R, T, rho0, beta, out);
}